// Round 1
// baseline (403.246 us; speedup 1.0000x reference)
//
#include <hip/hip_runtime.h>

#define T_LEN 2048
#define D_DIM 1024
#define R_DIM 64
#define B_DIM 4
#define BT_DIM 8192  // B*T

typedef __attribute__((ext_vector_type(8))) short s16x8;
typedef __attribute__((ext_vector_type(4))) float f32x4;

typedef __attribute__((address_space(1))) void gvoid_t;
typedef __attribute__((address_space(3))) void svoid_t;

__device__ __forceinline__ unsigned short f2bf(float f) {
  unsigned int u = __builtin_bit_cast(unsigned int, f);
  u += 0x7fffu + ((u >> 16) & 1u);
  return (unsigned short)(u >> 16);
}

__device__ __forceinline__ void gload16(const void* g, void* l) {
  __builtin_amdgcn_global_load_lds((gvoid_t*)g, (svoid_t*)l, 16, 0, 0);
}

// ---------------------------------------------------------------------------
// GEMM: C[m,n] = sum_k A[m,k]*B[n,k]   (A:[M,K] bf16, B:[N,K] bf16)
// 128x128 tile, BK=64, 256 threads (4 waves, 2x2), 16x16x32 bf16 MFMA.
// EPI: 0 = fp32 out, 1 = bf16 out, 2 = bf16 out with (/count + bias_eff)
// ---------------------------------------------------------------------------
template<int EPI>
__device__ __forceinline__ void gemm_body(
    const unsigned short* __restrict__ A, const unsigned short* __restrict__ B,
    void* __restrict__ Cv, int N, int K, int m0, int n0,
    const float* __restrict__ bias_b, const float* __restrict__ bias_t,
    const float* __restrict__ abi_p, const float* __restrict__ atri_p)
{
  __shared__ unsigned short As[128 * 64];
  __shared__ unsigned short Bs[128 * 64];
  const int tid  = threadIdx.x;
  const int wave = tid >> 6;
  const int lane = tid & 63;
  const int wr = wave >> 1, wc = wave & 1;
  const int trow = tid >> 3;          // 0..31
  const int tcol = (tid & 7) << 3;    // k-offset 0..56

  const unsigned short* Ap = A + (size_t)(m0 + trow) * K + tcol;
  const unsigned short* Bp = B + (size_t)(n0 + trow) * K + tcol;
  char* AsD = (char*)As + wave * 1024;
  char* BsD = (char*)Bs + wave * 1024;

  f32x4 acc[4][4] = {};

  for (int kt = 0; kt < K; kt += 64) {
#pragma unroll
    for (int it = 0; it < 4; ++it) {
      gload16(Ap + (size_t)it * 32 * K + kt, AsD + it * 4096);
      gload16(Bp + (size_t)it * 32 * K + kt, BsD + it * 4096);
    }
    __syncthreads();
#pragma unroll
    for (int ks = 0; ks < 2; ++ks) {
      const int kk = (ks << 5) + ((lane >> 4) << 3);
      const int ra = (wr << 6) + (lane & 15);
      const int rb = (wc << 6) + (lane & 15);
      s16x8 af[4], bfr[4];
#pragma unroll
      for (int i = 0; i < 4; ++i)
        af[i] = *(const s16x8*)&As[(ra + (i << 4)) * 64 + kk];
#pragma unroll
      for (int i = 0; i < 4; ++i)
        bfr[i] = *(const s16x8*)&Bs[(rb + (i << 4)) * 64 + kk];
#pragma unroll
      for (int i = 0; i < 4; ++i)
#pragma unroll
        for (int j = 0; j < 4; ++j)
          acc[i][j] = __builtin_amdgcn_mfma_f32_16x16x32_bf16(af[i], bfr[j], acc[i][j], 0, 0, 0);
    }
    __syncthreads();
  }

  // Epilogue. C/D layout (m89-verified): col = lane&15, row = (lane>>4)*4 + reg
  if (EPI == 0) {
    float* C = (float*)Cv;
#pragma unroll
    for (int i = 0; i < 4; ++i) {
      const int r0 = m0 + (wr << 6) + (i << 4) + ((lane >> 4) << 2);
#pragma unroll
      for (int j = 0; j < 4; ++j) {
        const int c = n0 + (wc << 6) + (j << 4) + (lane & 15);
#pragma unroll
        for (int rr = 0; rr < 4; ++rr)
          C[(size_t)(r0 + rr) * N + c] = acc[i][j][rr];
      }
    }
  } else if (EPI == 1) {
    unsigned short* C = (unsigned short*)Cv;
#pragma unroll
    for (int i = 0; i < 4; ++i) {
      const int r0 = m0 + (wr << 6) + (i << 4) + ((lane >> 4) << 2);
#pragma unroll
      for (int j = 0; j < 4; ++j) {
        const int c = n0 + (wc << 6) + (j << 4) + (lane & 15);
#pragma unroll
        for (int rr = 0; rr < 4; ++rr)
          C[(size_t)(r0 + rr) * N + c] = f2bf(acc[i][j][rr]);
      }
    }
  } else {
    unsigned short* C = (unsigned short*)Cv;
    const float abi = abi_p[0], atri = atri_p[0];
    float beff[4];
#pragma unroll
    for (int j = 0; j < 4; ++j) {
      const int c = n0 + (wc << 6) + (j << 4) + (lane & 15);
      beff[j] = (1.f + abi) * bias_b[c] + atri * bias_t[c];
    }
#pragma unroll
    for (int i = 0; i < 4; ++i) {
      const int r0 = m0 + (wr << 6) + (i << 4) + ((lane >> 4) << 2);
#pragma unroll
      for (int rr = 0; rr < 4; ++rr) {
        const int row = r0 + rr;
        const float inv = 1.0f / (float)((row & (T_LEN - 1)) + 1);
#pragma unroll
        for (int j = 0; j < 4; ++j) {
          const int c = n0 + (wc << 6) + (j << 4) + (lane & 15);
          C[(size_t)row * N + c] = f2bf(acc[i][j][rr] * inv + beff[j]);
        }
      }
    }
  }
}

template<int EPI>
__global__ __launch_bounds__(256) void gemm_bt_k(
    const unsigned short* __restrict__ A, const unsigned short* __restrict__ B,
    void* __restrict__ C, int N, int K,
    const float* __restrict__ bb, const float* __restrict__ bt,
    const float* __restrict__ abi, const float* __restrict__ atri)
{
  gemm_body<EPI>(A, B, C, N, K, blockIdx.x * 128, blockIdx.y * 128, bb, bt, abi, atri);
}

// Five rank-projection GEMMs fused into one launch (blockIdx.y selects).
__global__ __launch_bounds__(256) void rank5_k(
    const unsigned short* Qb, const unsigned short* Kb,
    const unsigned short* iKb, const unsigned short* iQb, const unsigned short* zb,
    const unsigned short* BQ, const unsigned short* BK,
    const unsigned short* BI, const unsigned short* BZ,
    float* PQ, float* PK, float* P3, float* P4, float* PZ)
{
  const unsigned short* A; const unsigned short* B; float* C;
  switch (blockIdx.y) {
    case 0:  A = Qb;  B = BQ; C = PQ; break;
    case 1:  A = Kb;  B = BK; C = PK; break;
    case 2:  A = iKb; B = BI; C = P3; break;
    case 3:  A = iQb; B = BI; C = P4; break;
    default: A = zb;  B = BZ; C = PZ; break;
  }
  gemm_body<0>(A, B, C, 128, 1024, blockIdx.x * 128, 0,
               nullptr, nullptr, nullptr, nullptr);
}

// ---------------------------------------------------------------------------
// Prep kernels
// ---------------------------------------------------------------------------
__global__ void cast_x_k(const float* __restrict__ s, unsigned short* __restrict__ d, int n4) {
  int i = blockIdx.x * 256 + threadIdx.x;
  if (i >= n4) return;
  float4 v = ((const float4*)s)[i];
  ushort4 o;
  o.x = f2bf(v.x); o.y = f2bf(v.y); o.z = f2bf(v.z); o.w = f2bf(v.w);
  ((ushort4*)d)[i] = o;
}

__global__ void cast4_k(const float* s0, const float* s1, const float* s2, const float* s3,
                        unsigned short* d0, unsigned short* d1,
                        unsigned short* d2, unsigned short* d3) {
  const float* s; unsigned short* d;
  switch (blockIdx.y) {
    case 0: s = s0; d = d0; break;
    case 1: s = s1; d = d1; break;
    case 2: s = s2; d = d2; break;
    default: s = s3; d = d3; break;
  }
  int i = blockIdx.x * 256 + threadIdx.x;   // grid.x = 1024 -> 262144 float4s
  float4 v = ((const float4*)s)[i];
  ushort4 o;
  o.x = f2bf(v.x); o.y = f2bf(v.y); o.z = f2bf(v.z); o.w = f2bf(v.w);
  ((ushort4*)d)[i] = o;
}

// B-panels [128][1024]: dst[n][k] = (n<64 ? s0 : s1)[k*64 + (n&63)]
__global__ void build4_k(const float* Vb, const float* Wb, const float* Vt,
                         const float* Wt, const float* Xt,
                         unsigned short* BQ, unsigned short* BK,
                         unsigned short* BI, unsigned short* BZ) {
  const float *s0, *s1; unsigned short* d;
  switch (blockIdx.y) {
    case 0:  s0 = Vb; s1 = Vt; d = BQ; break;
    case 1:  s0 = Wb; s1 = Wt; d = BK; break;
    case 2:  s0 = Vb; s1 = Wb; d = BI; break;
    default: s0 = Xt; s1 = Xt; d = BZ; break;
  }
  int idx = blockIdx.x * 256 + threadIdx.x;   // grid.x = 512 -> 131072
  int n = idx >> 10, k = idx & 1023;
  const float* s = (n < 64) ? s0 : s1;
  d[idx] = f2bf(s[k * 64 + (n & 63)]);
}

// Ucat [1024][128]: dst[n][k] = k<64 ? U_b[n][k] : U_t[n][k-64]
__global__ void build_ucat_k(const float* __restrict__ ub, const float* __restrict__ ut,
                             unsigned short* __restrict__ dst) {
  int idx = blockIdx.x * 256 + threadIdx.x;   // 131072
  int n = idx >> 7, k = idx & 127;
  dst[idx] = f2bf(k < 64 ? ub[n * 64 + k] : ut[n * 64 + k - 64]);
}

// ---------------------------------------------------------------------------
// z = cumsum(x, axis=T)/counts, two-pass over T (chunks of 128)
// ---------------------------------------------------------------------------
__global__ void zsum1_k(const float* __restrict__ x, float* __restrict__ psum) {
  const int d = blockIdx.x * 256 + threadIdx.x;
  const int tc = blockIdx.y, b = blockIdx.z;
  const float* xp = x + ((size_t)b * T_LEN + tc * 128) * D_DIM + d;
  float s = 0.f;
#pragma unroll 8
  for (int t = 0; t < 128; ++t) s += xp[(size_t)t * D_DIM];
  psum[(b * 16 + tc) * D_DIM + d] = s;
}

__global__ void zscan2_k(const float* __restrict__ x, const float* __restrict__ psum,
                         unsigned short* __restrict__ zb) {
  const int d = blockIdx.x * 256 + threadIdx.x;
  const int tc = blockIdx.y, b = blockIdx.z;
  float acc = 0.f;
  for (int i = 0; i < tc; ++i) acc += psum[(b * 16 + i) * D_DIM + d];
  const size_t base = ((size_t)b * T_LEN + tc * 128) * D_DIM + d;
  const float* xp = x + base;
  unsigned short* zp = zb + base;
#pragma unroll 4
  for (int t = 0; t < 128; ++t) {
    acc += xp[(size_t)t * D_DIM];
    const int tt = tc * 128 + t;
    zp[(size_t)t * D_DIM] = f2bf(acc / (float)(tt + 1));
  }
}

// ---------------------------------------------------------------------------
// Causal scans of P2,P3,P6 + elementwise combine -> rcat bf16 [8192][128]
// One wave per (b, r): lanes run over t, wave-scan via shfl_up.
// ---------------------------------------------------------------------------
__global__ __launch_bounds__(256) void scan_combine_k(
    const float* __restrict__ PQ, const float* __restrict__ PK,
    const float* __restrict__ P3, const float* __restrict__ P4,
    const float* __restrict__ PZ, const float* __restrict__ abi_p,
    const float* __restrict__ atri_p, unsigned short* __restrict__ rcat)
{
  const int wid  = blockIdx.x * 4 + (threadIdx.x >> 6);  // 0..255
  const int lane = threadIdx.x & 63;
  const int b = wid >> 6;
  const int r = wid & 63;
  const float abi = abi_p[0], atri = atri_p[0];
  float c2 = 0.f, c3 = 0.f, c6 = 0.f;
  for (int t0 = 0; t0 < T_LEN; t0 += 64) {
    const size_t row = (size_t)b * T_LEN + t0 + lane;
    const float p1 = PQ[row * 128 + r];
    const float p5 = PQ[row * 128 + 64 + r];
    float       s2 = PK[row * 128 + r];
    float       s6 = PK[row * 128 + 64 + r];
    float       s3 = P3[row * 128 + r];
    const float p4 = P4[row * 128 + 64 + r];
    const float p7 = PZ[row * 128 + r];
#pragma unroll
    for (int off = 1; off < 64; off <<= 1) {
      const float u2 = __shfl_up(s2, off);
      const float u3 = __shfl_up(s3, off);
      const float u6 = __shfl_up(s6, off);
      if (lane >= off) { s2 += u2; s3 += u3; s6 += u6; }
    }
    const float t2 = __shfl(s2, 63), t3 = __shfl(s3, 63), t6 = __shfl(s6, 63);
    s2 += c2; s3 += c3; s6 += c6;
    c2 += t2; c3 += t3; c6 += t6;
    const float rb = p1 * s2 + abi * (s3 * p4);
    const float rt = atri * (p5 * s6 * p7);
    rcat[row * 128 + r]      = f2bf(rb);
    rcat[row * 128 + 64 + r] = f2bf(rt);
  }
}

// ---------------------------------------------------------------------------
extern "C" void kernel_launch(void* const* d_in, const int* in_sizes, int n_in,
                              void* d_out, int out_size, void* d_ws, size_t ws_size,
                              hipStream_t stream)
{
  const float* x      = (const float*)d_in[0];
  const float* WQ     = (const float*)d_in[1];
  const float* WK     = (const float*)d_in[2];
  const float* WO     = (const float*)d_in[3];
  const float* Winv   = (const float*)d_in[4];
  const float* U_b    = (const float*)d_in[5];
  const float* V_b    = (const float*)d_in[6];
  const float* W_b    = (const float*)d_in[7];
  const float* bias_b = (const float*)d_in[8];
  const float* U_t    = (const float*)d_in[9];
  const float* V_t    = (const float*)d_in[10];
  const float* W_t    = (const float*)d_in[11];
  const float* X_t    = (const float*)d_in[12];
  const float* bias_t = (const float*)d_in[13];
  const float* a_bi   = (const float*)d_in[14];
  const float* a_tri  = (const float*)d_in[15];

  char* ws = (char*)d_ws;
  const size_t SZ_BTD = (size_t)BT_DIM * D_DIM * 2;  // 16 MiB bf16 [8192][1024]
  unsigned short* xb  = (unsigned short*)(ws + 0 * SZ_BTD);
  unsigned short* Qb  = (unsigned short*)(ws + 1 * SZ_BTD);
  unsigned short* Kb  = (unsigned short*)(ws + 2 * SZ_BTD);
  unsigned short* iQb = (unsigned short*)(ws + 3 * SZ_BTD);
  unsigned short* iKb = (unsigned short*)(ws + 4 * SZ_BTD);
  unsigned short* zb  = (unsigned short*)(ws + 5 * SZ_BTD);
  size_t off = 6 * SZ_BTD;
  unsigned short* WQb   = (unsigned short*)(ws + off); off += 2097152;
  unsigned short* WKb   = (unsigned short*)(ws + off); off += 2097152;
  unsigned short* WOb   = (unsigned short*)(ws + off); off += 2097152;
  unsigned short* Winvb = (unsigned short*)(ws + off); off += 2097152;
  unsigned short* BQ    = (unsigned short*)(ws + off); off += 262144;
  unsigned short* BK    = (unsigned short*)(ws + off); off += 262144;
  unsigned short* BI    = (unsigned short*)(ws + off); off += 262144;
  unsigned short* BZ    = (unsigned short*)(ws + off); off += 262144;
  unsigned short* Ucat  = (unsigned short*)(ws + off); off += 262144;
  float* PQ = (float*)(ws + off); off += 4194304;
  float* PK = (float*)(ws + off); off += 4194304;
  float* P3 = (float*)(ws + off); off += 4194304;
  float* P4 = (float*)(ws + off); off += 4194304;
  float* PZ = (float*)(ws + off); off += 4194304;
  unsigned short* rcatb = (unsigned short*)(ws + off); off += 2097152;
  float* psum = (float*)(ws + off); off += 262144;
  unsigned short* preb = Kb;  // alias: Kb is dead after rank5_k

  // ---- prep: casts / panel builds / z-scan ----
  cast_x_k<<<dim3(8192), 256, 0, stream>>>(x, xb, 2097152);
  cast4_k<<<dim3(1024, 4), 256, 0, stream>>>(WQ, WK, WO, Winv, WQb, WKb, WOb, Winvb);
  build4_k<<<dim3(512, 4), 256, 0, stream>>>(V_b, W_b, V_t, W_t, X_t, BQ, BK, BI, BZ);
  build_ucat_k<<<dim3(512), 256, 0, stream>>>(U_b, U_t, Ucat);
  zsum1_k<<<dim3(4, 16, 4), 256, 0, stream>>>(x, psum);
  zscan2_k<<<dim3(4, 16, 4), 256, 0, stream>>>(x, psum, zb);

  // ---- large GEMMs ----
  gemm_bt_k<1><<<dim3(64, 8), 256, 0, stream>>>(xb, WQb, Qb, 1024, 1024, nullptr, nullptr, nullptr, nullptr);
  gemm_bt_k<1><<<dim3(64, 8), 256, 0, stream>>>(xb, WKb, Kb, 1024, 1024, nullptr, nullptr, nullptr, nullptr);
  gemm_bt_k<1><<<dim3(64, 8), 256, 0, stream>>>(Qb, Winvb, iQb, 1024, 1024, nullptr, nullptr, nullptr, nullptr);
  gemm_bt_k<1><<<dim3(64, 8), 256, 0, stream>>>(Kb, Winvb, iKb, 1024, 1024, nullptr, nullptr, nullptr, nullptr);

  // ---- rank projections (5 fused) ----
  rank5_k<<<dim3(64, 5), 256, 0, stream>>>(Qb, Kb, iKb, iQb, zb, BQ, BK, BI, BZ,
                                           PQ, PK, P3, P4, PZ);

  // ---- causal scans + combine ----
  scan_combine_k<<<dim3(64), 256, 0, stream>>>(PQ, PK, P3, P4, PZ, a_bi, a_tri, rcatb);

  // ---- pre = rcat @ Ucat^T, /counts + bias fused in epilogue (bf16 out) ----
  gemm_bt_k<2><<<dim3(64, 8), 256, 0, stream>>>(rcatb, Ucat, preb, 1024, 128,
                                                bias_b, bias_t, a_bi, a_tri);

  // ---- out = preb @ WO^T (fp32 -> d_out) ----
  gemm_bt_k<0><<<dim3(64, 8), 256, 0, stream>>>(preb, WOb, d_out, 1024, 1024,
                                                nullptr, nullptr, nullptr, nullptr);
}

// Round 2
// 345.927 us; speedup vs baseline: 1.1657x; 1.1657x over previous
//
#include <hip/hip_runtime.h>

#define T_LEN 2048
#define D_DIM 1024
#define BT_DIM 8192  // B*T

typedef __attribute__((ext_vector_type(8))) short s16x8;
typedef __attribute__((ext_vector_type(4))) float f32x4;

typedef __attribute__((address_space(1))) void gvoid_t;
typedef __attribute__((address_space(3))) void svoid_t;

__device__ __forceinline__ unsigned short f2bf(float f) {
  unsigned int u = __builtin_bit_cast(unsigned int, f);
  u += 0x7fffu + ((u >> 16) & 1u);
  return (unsigned short)(u >> 16);
}

__device__ __forceinline__ void gload16(const void* g, void* l) {
  __builtin_amdgcn_global_load_lds((gvoid_t*)g, (svoid_t*)l, 16, 0, 0);
}

// ---------------------------------------------------------------------------
// GEMM: C[m,n] = sum_k A[m,k]*B[n,k]   (A:[M,lda] bf16, B:[N,ldb] bf16)
// 128x128 tile, BK=64, 256 threads (4 waves, 2x2), 16x16x32 bf16 MFMA.
// EPI: 0 = fp32 out, 1 = bf16 out, 2 = bf16 out with (/count + bias_eff)
// ---------------------------------------------------------------------------
template<int EPI>
__device__ __forceinline__ void gemm_body(
    const unsigned short* __restrict__ A, const unsigned short* __restrict__ B,
    void* __restrict__ Cv, int lda, int ldb, int ldc, int K, int m0, int n0,
    const float* __restrict__ bias_b, const float* __restrict__ bias_t,
    const float* __restrict__ abi_p, const float* __restrict__ atri_p)
{
  __shared__ unsigned short As[128 * 64];
  __shared__ unsigned short Bs[128 * 64];
  const int tid  = threadIdx.x;
  const int wave = tid >> 6;
  const int lane = tid & 63;
  const int wr = wave >> 1, wc = wave & 1;
  const int trow = tid >> 3;          // 0..31
  const int tcol = (tid & 7) << 3;    // k-offset 0..56

  const unsigned short* Ap = A + (size_t)(m0 + trow) * lda + tcol;
  const unsigned short* Bp = B + (size_t)(n0 + trow) * ldb + tcol;
  char* AsD = (char*)As + wave * 1024;
  char* BsD = (char*)Bs + wave * 1024;

  f32x4 acc[4][4] = {};

  for (int kt = 0; kt < K; kt += 64) {
#pragma unroll
    for (int it = 0; it < 4; ++it) {
      gload16(Ap + (size_t)it * 32 * lda + kt, AsD + it * 4096);
      gload16(Bp + (size_t)it * 32 * ldb + kt, BsD + it * 4096);
    }
    __syncthreads();
#pragma unroll
    for (int ks = 0; ks < 2; ++ks) {
      const int kk = (ks << 5) + ((lane >> 4) << 3);
      const int ra = (wr << 6) + (lane & 15);
      const int rb = (wc << 6) + (lane & 15);
      s16x8 af[4], bfr[4];
#pragma unroll
      for (int i = 0; i < 4; ++i)
        af[i] = *(const s16x8*)&As[(ra + (i << 4)) * 64 + kk];
#pragma unroll
      for (int i = 0; i < 4; ++i)
        bfr[i] = *(const s16x8*)&Bs[(rb + (i << 4)) * 64 + kk];
#pragma unroll
      for (int i = 0; i < 4; ++i)
#pragma unroll
        for (int j = 0; j < 4; ++j)
          acc[i][j] = __builtin_amdgcn_mfma_f32_16x16x32_bf16(af[i], bfr[j], acc[i][j], 0, 0, 0);
    }
    __syncthreads();
  }

  // Epilogue. C/D layout (m89-verified): col = lane&15, row = (lane>>4)*4 + reg
  if (EPI == 0) {
    float* C = (float*)Cv;
#pragma unroll
    for (int i = 0; i < 4; ++i) {
      const int r0 = m0 + (wr << 6) + (i << 4) + ((lane >> 4) << 2);
#pragma unroll
      for (int j = 0; j < 4; ++j) {
        const int c = n0 + (wc << 6) + (j << 4) + (lane & 15);
#pragma unroll
        for (int rr = 0; rr < 4; ++rr)
          C[(size_t)(r0 + rr) * ldc + c] = acc[i][j][rr];
      }
    }
  } else if (EPI == 1) {
    unsigned short* C = (unsigned short*)Cv;
#pragma unroll
    for (int i = 0; i < 4; ++i) {
      const int r0 = m0 + (wr << 6) + (i << 4) + ((lane >> 4) << 2);
#pragma unroll
      for (int j = 0; j < 4; ++j) {
        const int c = n0 + (wc << 6) + (j << 4) + (lane & 15);
#pragma unroll
        for (int rr = 0; rr < 4; ++rr)
          C[(size_t)(r0 + rr) * ldc + c] = f2bf(acc[i][j][rr]);
      }
    }
  } else {
    unsigned short* C = (unsigned short*)Cv;
    const float abi = abi_p[0], atri = atri_p[0];
    float beff[4];
#pragma unroll
    for (int j = 0; j < 4; ++j) {
      const int c = n0 + (wc << 6) + (j << 4) + (lane & 15);
      beff[j] = (1.f + abi) * bias_b[c] + atri * bias_t[c];
    }
#pragma unroll
    for (int i = 0; i < 4; ++i) {
      const int r0 = m0 + (wr << 6) + (i << 4) + ((lane >> 4) << 2);
#pragma unroll
      for (int rr = 0; rr < 4; ++rr) {
        const int row = r0 + rr;
        const float inv = 1.0f / (float)((row & (T_LEN - 1)) + 1);
#pragma unroll
        for (int j = 0; j < 4; ++j) {
          const int c = n0 + (wc << 6) + (j << 4) + (lane & 15);
          C[(size_t)row * ldc + c] = f2bf(acc[i][j][rr] * inv + beff[j]);
        }
      }
    }
  }
}

// a_zoff/c_zoff: element offsets applied per blockIdx.z (iQ/iK fusion)
template<int EPI>
__global__ __launch_bounds__(256) void gemm_bt_k(
    const unsigned short* __restrict__ A, const unsigned short* __restrict__ B,
    void* __restrict__ C, int lda, int ldb, int ldc, int K,
    int a_zoff, int c_zoff,
    const float* __restrict__ bb, const float* __restrict__ bt,
    const float* __restrict__ abi, const float* __restrict__ atri)
{
  const unsigned short* Az = A + (size_t)blockIdx.z * a_zoff;
  void* Cz = (char*)C + (size_t)blockIdx.z * c_zoff * (EPI == 0 ? 4 : 2);
  gemm_body<EPI>(Az, B, Cz, lda, ldb, ldc, K, blockIdx.x * 128, blockIdx.y * 128,
                 bb, bt, abi, atri);
}

// Five rank-projection GEMMs fused into one launch (blockIdx.y selects).
__global__ __launch_bounds__(256) void rank5_k(
    const unsigned short* QKb, const unsigned short* iQKb, const unsigned short* zb,
    const unsigned short* BQ, const unsigned short* BK,
    const unsigned short* BI, const unsigned short* BZ,
    float* PQ, float* PK, float* P3, float* P4, float* PZ)
{
  const unsigned short* A; const unsigned short* B; float* C; int lda;
  switch (blockIdx.y) {
    case 0:  A = QKb;          B = BQ; C = PQ; lda = 2048; break;  // Q
    case 1:  A = QKb + 1024;   B = BK; C = PK; lda = 2048; break;  // K
    case 2:  A = iQKb + 1024;  B = BI; C = P3; lda = 2048; break;  // iK
    case 3:  A = iQKb;         B = BI; C = P4; lda = 2048; break;  // iQ
    default: A = zb;           B = BZ; C = PZ; lda = 1024; break;  // z
  }
  gemm_body<0>(A, B, C, lda, 1024, 128, 1024, blockIdx.x * 128, 0,
               nullptr, nullptr, nullptr, nullptr);
}

// ---------------------------------------------------------------------------
// Prep kernels
// ---------------------------------------------------------------------------
__global__ void cast4_k(const float* s0, const float* s1, const float* s2, const float* s3,
                        unsigned short* d0, unsigned short* d1,
                        unsigned short* d2, unsigned short* d3) {
  const float* s; unsigned short* d;
  switch (blockIdx.y) {
    case 0: s = s0; d = d0; break;
    case 1: s = s1; d = d1; break;
    case 2: s = s2; d = d2; break;
    default: s = s3; d = d3; break;
  }
  int i = blockIdx.x * 256 + threadIdx.x;   // grid.x = 1024 -> 262144 float4s
  float4 v = ((const float4*)s)[i];
  ushort4 o;
  o.x = f2bf(v.x); o.y = f2bf(v.y); o.z = f2bf(v.z); o.w = f2bf(v.w);
  ((ushort4*)d)[i] = o;
}

// B-panels [128][1024]: dst[n][k] = (n<64 ? s0 : s1)[k*64 + (n&63)]
__global__ void build4_k(const float* Vb, const float* Wb, const float* Vt,
                         const float* Wt, const float* Xt,
                         unsigned short* BQ, unsigned short* BK,
                         unsigned short* BI, unsigned short* BZ) {
  const float *s0, *s1; unsigned short* d;
  switch (blockIdx.y) {
    case 0:  s0 = Vb; s1 = Vt; d = BQ; break;
    case 1:  s0 = Wb; s1 = Wt; d = BK; break;
    case 2:  s0 = Vb; s1 = Wb; d = BI; break;
    default: s0 = Xt; s1 = Xt; d = BZ; break;
  }
  int idx = blockIdx.x * 256 + threadIdx.x;   // grid.x = 512 -> 131072
  int n = idx >> 10, k = idx & 1023;
  const float* s = (n < 64) ? s0 : s1;
  d[idx] = f2bf(s[k * 64 + (n & 63)]);
}

// Ucat [1024][128]: dst[n][k] = k<64 ? U_b[n][k] : U_t[n][k-64]
__global__ void build_ucat_k(const float* __restrict__ ub, const float* __restrict__ ut,
                             unsigned short* __restrict__ dst) {
  int idx = blockIdx.x * 256 + threadIdx.x;   // 131072
  int n = idx >> 7, k = idx & 127;
  dst[idx] = f2bf(k < 64 ? ub[n * 64 + k] : ut[n * 64 + k - 64]);
}

// ---------------------------------------------------------------------------
// z = cumsum(x, axis=T)/counts, two-pass over T (chunks of 64); also emits xb.
// ---------------------------------------------------------------------------
__global__ void zsum1_k(const float* __restrict__ x, float* __restrict__ psum) {
  const int d = blockIdx.x * 256 + threadIdx.x;   // grid.x = 4
  const int tc = blockIdx.y, b = blockIdx.z;      // tc 0..31
  const float* xp = x + ((size_t)b * T_LEN + tc * 64) * D_DIM + d;
  float s = 0.f;
#pragma unroll 8
  for (int t = 0; t < 64; ++t) s += xp[(size_t)t * D_DIM];
  psum[((size_t)b * 32 + tc) * D_DIM + d] = s;
}

__global__ void zscan2_k(const float* __restrict__ x, const float* __restrict__ psum,
                         unsigned short* __restrict__ zb, unsigned short* __restrict__ xb) {
  const int d = blockIdx.x * 256 + threadIdx.x;
  const int tc = blockIdx.y, b = blockIdx.z;
  float acc = 0.f;
  for (int i = 0; i < tc; ++i) acc += psum[((size_t)b * 32 + i) * D_DIM + d];
  const size_t base = ((size_t)b * T_LEN + tc * 64) * D_DIM + d;
  const float* xp = x + base;
  unsigned short* zp = zb + base;
  unsigned short* xo = xb + base;
#pragma unroll 4
  for (int t = 0; t < 64; ++t) {
    const float v = xp[(size_t)t * D_DIM];
    xo[(size_t)t * D_DIM] = f2bf(v);
    acc += v;
    const int tt = tc * 64 + t;
    zp[(size_t)t * D_DIM] = f2bf(acc / (float)(tt + 1));
  }
}

// ---------------------------------------------------------------------------
// Causal scans, two-pass, lanes = r (coalesced). chunk = 32 rows, 64 chunks/b.
// ---------------------------------------------------------------------------
__global__ __launch_bounds__(256) void scanA_k(const float* __restrict__ PK,
                                               const float* __restrict__ P3,
                                               float* __restrict__ sums) {
  const int w = blockIdx.x * 4 + (threadIdx.x >> 6);  // 0..255
  const int lane = threadIdx.x & 63;
  const int b = w >> 6, ch = w & 63;
  const size_t row0 = (size_t)b * T_LEN + ch * 32;
  float s2 = 0.f, s6 = 0.f, s3 = 0.f;
#pragma unroll 4
  for (int t = 0; t < 32; ++t) {
    const size_t ro = (row0 + t) * 128;
    s2 += PK[ro + lane];
    s6 += PK[ro + 64 + lane];
    s3 += P3[ro + lane];
  }
  const size_t o = (size_t)(b * 64 + ch) * 192 + lane;
  sums[o] = s2; sums[o + 64] = s6; sums[o + 128] = s3;
}

__global__ __launch_bounds__(256) void scanB_k(
    const float* __restrict__ PQ, const float* __restrict__ PK,
    const float* __restrict__ P3, const float* __restrict__ P4,
    const float* __restrict__ PZ, const float* __restrict__ sums,
    const float* __restrict__ abi_p, const float* __restrict__ atri_p,
    unsigned short* __restrict__ rcat)
{
  const int w = blockIdx.x * 4 + (threadIdx.x >> 6);
  const int lane = threadIdx.x & 63;
  const int b = w >> 6, ch = w & 63;
  float c2 = 0.f, c6 = 0.f, c3 = 0.f;
  for (int i = 0; i < ch; ++i) {
    const size_t o = (size_t)(b * 64 + i) * 192 + lane;
    c2 += sums[o]; c6 += sums[o + 64]; c3 += sums[o + 128];
  }
  const float abi = abi_p[0], atri = atri_p[0];
  const size_t row0 = (size_t)b * T_LEN + ch * 32;
#pragma unroll 2
  for (int t = 0; t < 32; ++t) {
    const size_t ro = (row0 + t) * 128;
    const float p1 = PQ[ro + lane];
    const float p5 = PQ[ro + 64 + lane];
    c2 += PK[ro + lane];
    c6 += PK[ro + 64 + lane];
    c3 += P3[ro + lane];
    const float p4 = P4[ro + 64 + lane];
    const float p7 = PZ[ro + lane];
    const float rb = p1 * c2 + abi * (c3 * p4);
    const float rt = atri * (p5 * c6 * p7);
    rcat[ro + lane]      = f2bf(rb);
    rcat[ro + 64 + lane] = f2bf(rt);
  }
}

// ---------------------------------------------------------------------------
extern "C" void kernel_launch(void* const* d_in, const int* in_sizes, int n_in,
                              void* d_out, int out_size, void* d_ws, size_t ws_size,
                              hipStream_t stream)
{
  const float* x      = (const float*)d_in[0];
  const float* WQ     = (const float*)d_in[1];
  const float* WK     = (const float*)d_in[2];
  const float* WO     = (const float*)d_in[3];
  const float* Winv   = (const float*)d_in[4];
  const float* U_b    = (const float*)d_in[5];
  const float* V_b    = (const float*)d_in[6];
  const float* W_b    = (const float*)d_in[7];
  const float* bias_b = (const float*)d_in[8];
  const float* U_t    = (const float*)d_in[9];
  const float* V_t    = (const float*)d_in[10];
  const float* W_t    = (const float*)d_in[11];
  const float* X_t    = (const float*)d_in[12];
  const float* bias_t = (const float*)d_in[13];
  const float* a_bi   = (const float*)d_in[14];
  const float* a_tri  = (const float*)d_in[15];

  char* ws = (char*)d_ws;
  size_t off = 0;
  unsigned short* xb    = (unsigned short*)(ws + off); off += (size_t)BT_DIM * 1024 * 2;  // 16MB
  unsigned short* QKb   = (unsigned short*)(ws + off); off += (size_t)BT_DIM * 2048 * 2;  // 32MB
  unsigned short* iQKb  = (unsigned short*)(ws + off); off += (size_t)BT_DIM * 2048 * 2;  // 32MB
  unsigned short* zb    = (unsigned short*)(ws + off); off += (size_t)BT_DIM * 1024 * 2;  // 16MB
  unsigned short* WQb   = (unsigned short*)(ws + off); off += 2097152;  // [WQ|
  unsigned short* WKb   = (unsigned short*)(ws + off); off += 2097152;  //  WK] adjacent -> N=2048 panel
  unsigned short* WOb   = (unsigned short*)(ws + off); off += 2097152;
  unsigned short* Winvb = (unsigned short*)(ws + off); off += 2097152;
  unsigned short* BQ    = (unsigned short*)(ws + off); off += 262144;
  unsigned short* BK    = (unsigned short*)(ws + off); off += 262144;
  unsigned short* BI    = (unsigned short*)(ws + off); off += 262144;
  unsigned short* BZ    = (unsigned short*)(ws + off); off += 262144;
  unsigned short* Ucat  = (unsigned short*)(ws + off); off += 262144;
  float* PQ = (float*)(ws + off); off += 4194304;
  float* PK = (float*)(ws + off); off += 4194304;
  float* P3 = (float*)(ws + off); off += 4194304;
  float* P4 = (float*)(ws + off); off += 4194304;
  float* PZ = (float*)(ws + off); off += 4194304;
  unsigned short* rcatb = (unsigned short*)(ws + off); off += 2097152;
  float* sums = (float*)(ws + off); off += 196608;   // 256 chunks * 192 f32
  float* psum = (float*)(ws + off); off += 524288;   // 4*32*1024 f32
  unsigned short* preb = QKb;  // alias: QKb dead after rank5_k

  // ---- prep ----
  cast4_k<<<dim3(1024, 4), 256, 0, stream>>>(WQ, WK, WO, Winv, WQb, WKb, WOb, Winvb);
  build4_k<<<dim3(512, 4), 256, 0, stream>>>(V_b, W_b, V_t, W_t, X_t, BQ, BK, BI, BZ);
  build_ucat_k<<<dim3(512), 256, 0, stream>>>(U_b, U_t, Ucat);
  zsum1_k<<<dim3(4, 32, 4), 256, 0, stream>>>(x, psum);
  zscan2_k<<<dim3(4, 32, 4), 256, 0, stream>>>(x, psum, zb, xb);

  // ---- QK = x @ [WQ|WK]^T  (M=8192, N=2048, K=1024) ----
  gemm_bt_k<1><<<dim3(64, 16), 256, 0, stream>>>(xb, WQb, QKb, 1024, 1024, 2048, 1024,
                                                 0, 0, nullptr, nullptr, nullptr, nullptr);
  // ---- iQK = [Q|K] @ Winv^T  (two M=8192 slabs via blockIdx.z) ----
  gemm_bt_k<1><<<dim3(64, 8, 2), 256, 0, stream>>>(QKb, Winvb, iQKb, 2048, 1024, 2048, 1024,
                                                   1024, 1024, nullptr, nullptr, nullptr, nullptr);

  // ---- rank projections (5 fused) ----
  rank5_k<<<dim3(64, 5), 256, 0, stream>>>(QKb, iQKb, zb, BQ, BK, BI, BZ,
                                           PQ, PK, P3, P4, PZ);

  // ---- causal scans + combine (two-pass, coalesced) ----
  scanA_k<<<dim3(64), 256, 0, stream>>>(PK, P3, sums);
  scanB_k<<<dim3(64), 256, 0, stream>>>(PQ, PK, P3, P4, PZ, sums, a_bi, a_tri, rcatb);

  // ---- pre = rcat @ Ucat^T, /counts + bias fused (bf16 out) ----
  gemm_bt_k<2><<<dim3(64, 8), 256, 0, stream>>>(rcatb, Ucat, preb, 128, 128, 1024, 128,
                                                0, 0, bias_b, bias_t, a_bi, a_tri);

  // ---- out = preb @ WO^T (fp32 -> d_out) ----
  gemm_bt_k<0><<<dim3(64, 8), 256, 0, stream>>>(preb, WOb, d_out, 1024, 1024, 1024, 1024,
                                                0, 0, nullptr, nullptr, nullptr, nullptr);
}

// Round 3
// 235.523 us; speedup vs baseline: 1.7121x; 1.4688x over previous
//
#include <hip/hip_runtime.h>

#define T_LEN 2048
#define D_DIM 1024
#define BT_DIM 8192  // B*T

typedef __attribute__((ext_vector_type(8))) short s16x8;
typedef __attribute__((ext_vector_type(4))) float f32x4;

typedef __attribute__((address_space(1))) void gvoid_t;
typedef __attribute__((address_space(3))) void svoid_t;

__device__ __forceinline__ unsigned short f2bf(float f) {
  unsigned int u = __builtin_bit_cast(unsigned int, f);
  u += 0x7fffu + ((u >> 16) & 1u);
  return (unsigned short)(u >> 16);
}

__device__ __forceinline__ void gload16(const void* g, void* l) {
  __builtin_amdgcn_global_load_lds((gvoid_t*)g, (svoid_t*)l, 16, 0, 0);
}

// ---------------------------------------------------------------------------
// GEMM: C[m,n] = sum_k A[m,k]*B[n,k]   (A:[M,lda] bf16, B:[N,ldb] bf16)
// 128x128 tile, BK=64, 256 threads (4 waves, 2x2), 16x16x32 bf16 MFMA.
// EPI: 0 = fp32 out, 1 = bf16 out, 3 = fp32 out + obias[col]
// ---------------------------------------------------------------------------
template<int EPI>
__device__ __forceinline__ void gemm_body(
    const unsigned short* __restrict__ A, const unsigned short* __restrict__ B,
    void* __restrict__ Cv, int lda, int ldb, int ldc, int K, int m0, int n0,
    const float* __restrict__ obias)
{
  __shared__ unsigned short As[128 * 64];
  __shared__ unsigned short Bs[128 * 64];
  const int tid  = threadIdx.x;
  const int wave = tid >> 6;
  const int lane = tid & 63;
  const int wr = wave >> 1, wc = wave & 1;
  const int trow = tid >> 3;          // 0..31
  const int tcol = (tid & 7) << 3;    // k-offset 0..56

  const unsigned short* Ap = A + (size_t)(m0 + trow) * lda + tcol;
  const unsigned short* Bp = B + (size_t)(n0 + trow) * ldb + tcol;
  char* AsD = (char*)As + wave * 1024;
  char* BsD = (char*)Bs + wave * 1024;

  f32x4 acc[4][4] = {};

  for (int kt = 0; kt < K; kt += 64) {
#pragma unroll
    for (int it = 0; it < 4; ++it) {
      gload16(Ap + (size_t)it * 32 * lda + kt, AsD + it * 4096);
      gload16(Bp + (size_t)it * 32 * ldb + kt, BsD + it * 4096);
    }
    __syncthreads();
#pragma unroll
    for (int ks = 0; ks < 2; ++ks) {
      const int kk = (ks << 5) + ((lane >> 4) << 3);
      const int ra = (wr << 6) + (lane & 15);
      const int rb = (wc << 6) + (lane & 15);
      s16x8 af[4], bfr[4];
#pragma unroll
      for (int i = 0; i < 4; ++i)
        af[i] = *(const s16x8*)&As[(ra + (i << 4)) * 64 + kk];
#pragma unroll
      for (int i = 0; i < 4; ++i)
        bfr[i] = *(const s16x8*)&Bs[(rb + (i << 4)) * 64 + kk];
#pragma unroll
      for (int i = 0; i < 4; ++i)
#pragma unroll
        for (int j = 0; j < 4; ++j)
          acc[i][j] = __builtin_amdgcn_mfma_f32_16x16x32_bf16(af[i], bfr[j], acc[i][j], 0, 0, 0);
    }
    __syncthreads();
  }

  // Epilogue. C/D layout (m89-verified): col = lane&15, row = (lane>>4)*4 + reg
  if (EPI == 0) {
    float* C = (float*)Cv;
#pragma unroll
    for (int i = 0; i < 4; ++i) {
      const int r0 = m0 + (wr << 6) + (i << 4) + ((lane >> 4) << 2);
#pragma unroll
      for (int j = 0; j < 4; ++j) {
        const int c = n0 + (wc << 6) + (j << 4) + (lane & 15);
#pragma unroll
        for (int rr = 0; rr < 4; ++rr)
          C[(size_t)(r0 + rr) * ldc + c] = acc[i][j][rr];
      }
    }
  } else if (EPI == 1) {
    unsigned short* C = (unsigned short*)Cv;
#pragma unroll
    for (int i = 0; i < 4; ++i) {
      const int r0 = m0 + (wr << 6) + (i << 4) + ((lane >> 4) << 2);
#pragma unroll
      for (int j = 0; j < 4; ++j) {
        const int c = n0 + (wc << 6) + (j << 4) + (lane & 15);
#pragma unroll
        for (int rr = 0; rr < 4; ++rr)
          C[(size_t)(r0 + rr) * ldc + c] = f2bf(acc[i][j][rr]);
      }
    }
  } else {
    float* C = (float*)Cv;
    float ob[4];
#pragma unroll
    for (int j = 0; j < 4; ++j)
      ob[j] = obias[n0 + (wc << 6) + (j << 4) + (lane & 15)];
#pragma unroll
    for (int i = 0; i < 4; ++i) {
      const int r0 = m0 + (wr << 6) + (i << 4) + ((lane >> 4) << 2);
#pragma unroll
      for (int j = 0; j < 4; ++j) {
        const int c = n0 + (wc << 6) + (j << 4) + (lane & 15);
#pragma unroll
        for (int rr = 0; rr < 4; ++rr)
          C[(size_t)(r0 + rr) * ldc + c] = acc[i][j][rr] + ob[j];
      }
    }
  }
}

// ---------------------------------------------------------------------------
// Weight-fold GEMMs (tiny). smallA: G_PQ, G_PK, H_b, Gfin. smallB: G_P3, G_P4.
// ---------------------------------------------------------------------------
__global__ __launch_bounds__(256) void smallA_k(
    const unsigned short* BQ, const unsigned short* BK, const unsigned short* BI,
    const unsigned short* WOb, const unsigned short* WQt, const unsigned short* WKt,
    const unsigned short* Winvt, const unsigned short* UcatT,
    unsigned short* Gcat, unsigned short* Hb, unsigned short* Gfin)
{
  const int bx = blockIdx.x;
  switch (blockIdx.y) {
    case 0:  gemm_body<1>(BQ, WQt, Gcat,               1024, 1024, 1024, 1024, 0, bx * 128, nullptr); break;
    case 1:  gemm_body<1>(BK, WKt, Gcat + 128 * 1024,  1024, 1024, 1024, 1024, 0, bx * 128, nullptr); break;
    case 2:  gemm_body<1>(BI, Winvt, Hb,               1024, 1024, 1024, 1024, 0, bx * 128, nullptr); break;
    default: gemm_body<1>(WOb, UcatT, Gfin,            1024, 1024, 128, 1024, bx * 128, 0, nullptr); break;
  }
}

__global__ __launch_bounds__(256) void smallB_k(
    const unsigned short* Hb, const unsigned short* WKt, const unsigned short* WQt,
    unsigned short* Gcat)
{
  const int bx = blockIdx.x;
  if (blockIdx.y == 0)
    gemm_body<1>(Hb, WKt, Gcat + 256 * 1024, 1024, 1024, 1024, 1024, 0, bx * 128, nullptr);
  else
    gemm_body<1>(Hb, WQt, Gcat + 384 * 1024, 1024, 1024, 1024, 1024, 0, bx * 128, nullptr);
}

// Main rank projection: Pcat[8192][640] fp32 = xb @ Gcat^T (5 column groups)
__global__ __launch_bounds__(256) void mainP_k(
    const unsigned short* __restrict__ xb, const unsigned short* __restrict__ Gcat,
    float* __restrict__ Pcat)
{
  const int y = blockIdx.y;
  gemm_body<0>(xb, Gcat + (size_t)y * 128 * 1024, Pcat + y * 128,
               1024, 1024, 640, 1024, blockIdx.x * 128, 0, nullptr);
}

// Final: out = rcat @ Gfin^T + obias  (M=8192, N=1024, K=128)
__global__ __launch_bounds__(256) void final_k(
    const unsigned short* __restrict__ rcat, const unsigned short* __restrict__ Gfin,
    const float* __restrict__ obias, float* __restrict__ out)
{
  gemm_body<3>(rcat, Gfin, out, 128, 128, 1024, 128,
               blockIdx.x * 128, blockIdx.y * 128, obias);
}

// ---------------------------------------------------------------------------
// Prep kernels
// ---------------------------------------------------------------------------
__global__ void cast_x_k(const float* __restrict__ s, unsigned short* __restrict__ d, int n4) {
  int i = blockIdx.x * 256 + threadIdx.x;
  if (i >= n4) return;
  float4 v = ((const float4*)s)[i];
  ushort4 o;
  o.x = f2bf(v.x); o.y = f2bf(v.y); o.z = f2bf(v.z); o.w = f2bf(v.w);
  ((ushort4*)d)[i] = o;
}

__global__ void cast_wo_k(const float* __restrict__ s, unsigned short* __restrict__ d) {
  int i = blockIdx.x * 256 + threadIdx.x;  // grid 1024 -> 262144 float4
  float4 v = ((const float4*)s)[i];
  ushort4 o;
  o.x = f2bf(v.x); o.y = f2bf(v.y); o.z = f2bf(v.z); o.w = f2bf(v.w);
  ((ushort4*)d)[i] = o;
}

// Transpose+cast three 1024x1024 fp32 -> bf16 (dst[d][k] = src[k][d])
__global__ __launch_bounds__(256) void tr_k(
    const float* s0, const float* s1, const float* s2,
    unsigned short* d0, unsigned short* d1, unsigned short* d2)
{
  const float* s; unsigned short* d;
  switch (blockIdx.y) { case 0: s = s0; d = d0; break;
                        case 1: s = s1; d = d1; break;
                        default: s = s2; d = d2; break; }
  __shared__ float ld[64][65];
  const int tY = blockIdx.x >> 4, tX = blockIdx.x & 15;
  const int c = threadIdx.x & 63, g = threadIdx.x >> 6;
#pragma unroll
  for (int rr = 0; rr < 16; ++rr) {
    const int r = g * 16 + rr;
    ld[r][c] = s[(size_t)(tY * 64 + r) * 1024 + tX * 64 + c];
  }
  __syncthreads();
#pragma unroll
  for (int rr = 0; rr < 16; ++rr) {
    const int r = g * 16 + rr;
    d[(size_t)(tX * 64 + r) * 1024 + tY * 64 + c] = f2bf(ld[c][r]);
  }
}

// Rank A-panels [128][1024]: dst[n][k] = (n<64 ? s0 : s1)[k*64 + (n&63)]
__global__ void build3_k(const float* Vb, const float* Wb, const float* Vt,
                         const float* Wt,
                         unsigned short* BQ, unsigned short* BK, unsigned short* BI) {
  const float *s0, *s1; unsigned short* d;
  switch (blockIdx.y) {
    case 0:  s0 = Vb; s1 = Vt; d = BQ; break;
    case 1:  s0 = Wb; s1 = Wt; d = BK; break;
    default: s0 = Vb; s1 = Wb; d = BI; break;
  }
  int idx = blockIdx.x * 256 + threadIdx.x;   // grid.x = 512 -> 131072
  int n = idx >> 10, k = idx & 1023;
  const float* s = (n < 64) ? s0 : s1;
  d[idx] = f2bf(s[k * 64 + (n & 63)]);
}

// UcatT[128][1024] + X_t^T into Gcat rows 512..639 (dup rows 576..639)
__global__ void miscA_k(const float* U_b, const float* U_t, const float* X_t,
                        unsigned short* UcatT, unsigned short* Gcat) {
  int idx = blockIdx.x * 256 + threadIdx.x;   // grid.x = 512 -> 131072
  if (blockIdx.y == 0) {
    int k = idx >> 10, d = idx & 1023;
    UcatT[idx] = f2bf(k < 64 ? U_b[d * 64 + k] : U_t[d * 64 + k - 64]);
  } else {
    int r = idx >> 10, d = idx & 1023;
    Gcat[(size_t)512 * 1024 + idx] = f2bf(X_t[d * 64 + (r & 63)]);
  }
}

// obias[n] = sum_d ((1+abi)*bias_b[d] + atri*bias_t[d]) * WO[n][d]
__global__ __launch_bounds__(256) void obias_k(
    const float* __restrict__ WO, const float* __restrict__ bias_b,
    const float* __restrict__ bias_t, const float* __restrict__ abi_p,
    const float* __restrict__ atri_p, float* __restrict__ obias)
{
  const int n = blockIdx.x, tid = threadIdx.x;
  const float abi = abi_p[0], atri = atri_p[0];
  float s = 0.f;
  for (int d = tid; d < 1024; d += 256)
    s += ((1.f + abi) * bias_b[d] + atri * bias_t[d]) * WO[(size_t)n * 1024 + d];
  __shared__ float red[256];
  red[tid] = s;
  __syncthreads();
#pragma unroll
  for (int w = 128; w > 0; w >>= 1) {
    if (tid < w) red[tid] += red[tid + w];
    __syncthreads();
  }
  if (tid == 0) obias[n] = red[0];
}

// ---------------------------------------------------------------------------
// Causal scans (4 streams) + combine, two-pass, lanes = r (coalesced).
// Pcat cols: 0:PQlo 64:PQhi 128:s2 192:s6 256:s3 448:p4 512:sZ  (ld=640)
// ---------------------------------------------------------------------------
__global__ __launch_bounds__(256) void scanA_k(const float* __restrict__ P,
                                               float* __restrict__ sums) {
  const int w = blockIdx.x * 4 + (threadIdx.x >> 6);  // 0..255
  const int lane = threadIdx.x & 63;
  const int b = w >> 6, ch = w & 63;
  const size_t row0 = (size_t)b * T_LEN + ch * 32;
  float s2 = 0.f, s6 = 0.f, s3 = 0.f, sZ = 0.f;
#pragma unroll 4
  for (int t = 0; t < 32; ++t) {
    const size_t ro = (row0 + t) * 640;
    s2 += P[ro + 128 + lane];
    s6 += P[ro + 192 + lane];
    s3 += P[ro + 256 + lane];
    sZ += P[ro + 512 + lane];
  }
  const size_t o = (size_t)(b * 64 + ch) * 256 + lane;
  sums[o] = s2; sums[o + 64] = s6; sums[o + 128] = s3; sums[o + 192] = sZ;
}

__global__ __launch_bounds__(256) void scanB_k(
    const float* __restrict__ P, const float* __restrict__ sums,
    const float* __restrict__ abi_p, const float* __restrict__ atri_p,
    unsigned short* __restrict__ rcat)
{
  const int w = blockIdx.x * 4 + (threadIdx.x >> 6);
  const int lane = threadIdx.x & 63;
  const int b = w >> 6, ch = w & 63;
  float c2 = 0.f, c6 = 0.f, c3 = 0.f, cZ = 0.f;
  for (int i = 0; i < ch; ++i) {
    const size_t o = (size_t)(b * 64 + i) * 256 + lane;
    c2 += sums[o]; c6 += sums[o + 64]; c3 += sums[o + 128]; cZ += sums[o + 192];
  }
  const float abi = abi_p[0], atri = atri_p[0];
  const size_t row0 = (size_t)b * T_LEN + ch * 32;
#pragma unroll 2
  for (int t = 0; t < 32; ++t) {
    const size_t ro = (row0 + t) * 640;
    const float p1 = P[ro + lane];
    const float p5 = P[ro + 64 + lane];
    c2 += P[ro + 128 + lane];
    c6 += P[ro + 192 + lane];
    c3 += P[ro + 256 + lane];
    cZ += P[ro + 512 + lane];
    const float p4 = P[ro + 448 + lane];
    const float invc = 1.0f / (float)(ch * 32 + t + 1);
    const float rb = (p1 * c2 + abi * (c3 * p4)) * invc;
    const float rt = atri * p5 * c6 * cZ * invc * invc;
    const size_t rro = (row0 + t) * 128;
    rcat[rro + lane]      = f2bf(rb);
    rcat[rro + 64 + lane] = f2bf(rt);
  }
}

// ---------------------------------------------------------------------------
extern "C" void kernel_launch(void* const* d_in, const int* in_sizes, int n_in,
                              void* d_out, int out_size, void* d_ws, size_t ws_size,
                              hipStream_t stream)
{
  const float* x      = (const float*)d_in[0];
  const float* WQ     = (const float*)d_in[1];
  const float* WK     = (const float*)d_in[2];
  const float* WO     = (const float*)d_in[3];
  const float* Winv   = (const float*)d_in[4];
  const float* U_b    = (const float*)d_in[5];
  const float* V_b    = (const float*)d_in[6];
  const float* W_b    = (const float*)d_in[7];
  const float* bias_b = (const float*)d_in[8];
  const float* U_t    = (const float*)d_in[9];
  const float* V_t    = (const float*)d_in[10];
  const float* W_t    = (const float*)d_in[11];
  const float* X_t    = (const float*)d_in[12];
  const float* bias_t = (const float*)d_in[13];
  const float* a_bi   = (const float*)d_in[14];
  const float* a_tri  = (const float*)d_in[15];

  char* ws = (char*)d_ws;
  size_t off = 0;
  unsigned short* xb    = (unsigned short*)(ws + off); off += (size_t)BT_DIM * 1024 * 2;   // 16MB
  float*          Pcat  = (float*)(ws + off);          off += (size_t)BT_DIM * 640 * 4;    // 21MB
  unsigned short* rcat  = (unsigned short*)(ws + off); off += (size_t)BT_DIM * 128 * 2;    // 2MB
  unsigned short* WQt   = (unsigned short*)(ws + off); off += 2097152;
  unsigned short* WKt   = (unsigned short*)(ws + off); off += 2097152;
  unsigned short* Winvt = (unsigned short*)(ws + off); off += 2097152;
  unsigned short* WOb   = (unsigned short*)(ws + off); off += 2097152;
  unsigned short* BQ    = (unsigned short*)(ws + off); off += 262144;
  unsigned short* BK    = (unsigned short*)(ws + off); off += 262144;
  unsigned short* BI    = (unsigned short*)(ws + off); off += 262144;
  unsigned short* Hb    = (unsigned short*)(ws + off); off += 262144;
  unsigned short* UcatT = (unsigned short*)(ws + off); off += 262144;
  unsigned short* Gcat  = (unsigned short*)(ws + off); off += (size_t)640 * 1024 * 2;      // 1.25MB
  unsigned short* Gfin  = (unsigned short*)(ws + off); off += 262144;
  float*          obias = (float*)(ws + off);          off += 4096;
  float*          sums  = (float*)(ws + off);          off += 262144;

  // ---- prep (independent) ----
  cast_x_k<<<dim3(8192), 256, 0, stream>>>(x, xb, 2097152);
  tr_k<<<dim3(256, 3), 256, 0, stream>>>(WQ, WK, Winv, WQt, WKt, Winvt);
  build3_k<<<dim3(512, 3), 256, 0, stream>>>(V_b, W_b, V_t, W_t, BQ, BK, BI);
  miscA_k<<<dim3(512, 2), 256, 0, stream>>>(U_b, U_t, X_t, UcatT, Gcat);
  cast_wo_k<<<dim3(1024), 256, 0, stream>>>(WO, WOb);
  obias_k<<<dim3(1024), 256, 0, stream>>>(WO, bias_b, bias_t, a_bi, a_tri, obias);

  // ---- weight folds ----
  smallA_k<<<dim3(8, 4), 256, 0, stream>>>(BQ, BK, BI, WOb, WQt, WKt, Winvt, UcatT,
                                           Gcat, Hb, Gfin);
  smallB_k<<<dim3(8, 2), 256, 0, stream>>>(Hb, WKt, WQt, Gcat);

  // ---- main rank projection: Pcat = xb @ Gcat^T ----
  mainP_k<<<dim3(64, 5), 256, 0, stream>>>(xb, Gcat, Pcat);

  // ---- causal scans + combine (writes rcat pre-scaled by 1/count) ----
  scanA_k<<<dim3(64), 256, 0, stream>>>(Pcat, sums);
  scanB_k<<<dim3(64), 256, 0, stream>>>(Pcat, sums, a_bi, a_tri, rcat);

  // ---- out = rcat @ Gfin^T + obias ----
  final_k<<<dim3(64, 8), 256, 0, stream>>>(rcat, Gfin, obias, (float*)d_out);
}

// Round 4
// 210.115 us; speedup vs baseline: 1.9192x; 1.1209x over previous
//
#include <hip/hip_runtime.h>

#define T_LEN 2048
#define BT_DIM 8192  // B*T

typedef __attribute__((ext_vector_type(8))) short s16x8;
typedef __attribute__((ext_vector_type(4))) float f32x4;

typedef __attribute__((address_space(1))) void gvoid_t;
typedef __attribute__((address_space(3))) void svoid_t;

__device__ __forceinline__ unsigned short f2bf(float f) {
  unsigned int u = __builtin_bit_cast(unsigned int, f);
  u += 0x7fffu + ((u >> 16) & 1u);
  return (unsigned short)(u >> 16);
}
__device__ __forceinline__ float bf2f(unsigned short u) {
  unsigned int v = (unsigned int)u << 16;
  return __builtin_bit_cast(float, v);
}
__device__ __forceinline__ void gload16(const void* g, void* l) {
  __builtin_amdgcn_global_load_lds((gvoid_t*)g, (svoid_t*)l, 16, 0, 0);
}

// ---------------------------------------------------------------------------
// GEMM core: C[m,n] = sum_k A[m,k]*B[n,k], 128x128 tile, BK=64, 4 waves,
// 2-phase double-buffered LDS (stage k+1 before compute k; one barrier/step).
// EPI: 2 = bf16 out, local-row window [rlo,rhi)
//      3 = f32 out + obias[col]
//      4 = bf16 out + chunk-sum side-writes into `sums` (mainP)
// ---------------------------------------------------------------------------
template<int EPI>
__device__ __forceinline__ void gemm_body(
    const unsigned short* __restrict__ A, const unsigned short* __restrict__ B,
    void* __restrict__ Cv, int lda, int ldb, int ldc, int K, int m0, int n0,
    const float* __restrict__ obias, float* __restrict__ sums, int ygrp,
    int rlo, int rhi)
{
  __shared__ unsigned short As[2 * 128 * 64];   // 2 x 16KB
  __shared__ unsigned short Bs[2 * 128 * 64];
  const int tid  = threadIdx.x;
  const int wave = tid >> 6;
  const int lane = tid & 63;
  const int wr = wave >> 1, wc = wave & 1;
  const int trow = tid >> 3;          // 0..31
  const int tcol = (tid & 7) << 3;    // k-offset 0..56

  const unsigned short* Ap = A + (size_t)(m0 + trow) * lda + tcol;
  const unsigned short* Bp = B + (size_t)(n0 + trow) * ldb + tcol;

  f32x4 acc[4][4] = {};

  auto stage = [&](int buf, int kt) {
    char* ab = (char*)As + buf * 16384 + wave * 1024;
    char* bb = (char*)Bs + buf * 16384 + wave * 1024;
#pragma unroll
    for (int it = 0; it < 4; ++it) {
      gload16(Ap + (size_t)it * 32 * lda + kt, ab + it * 4096);
      gload16(Bp + (size_t)it * 32 * ldb + kt, bb + it * 4096);
    }
  };

  stage(0, 0);
  __syncthreads();
  int cur = 0;
  for (int kt = 64; kt <= K; kt += 64) {
    if (kt < K) stage(cur ^ 1, kt);     // prefetch next tile (overlaps MFMA)
#pragma unroll
    for (int ks = 0; ks < 2; ++ks) {
      const int kk = (ks << 5) + ((lane >> 4) << 3);
      const int ra = (wr << 6) + (lane & 15);
      const int rb = (wc << 6) + (lane & 15);
      s16x8 af[4], bfr[4];
#pragma unroll
      for (int i = 0; i < 4; ++i)
        af[i] = *(const s16x8*)&As[cur * 8192 + (ra + (i << 4)) * 64 + kk];
#pragma unroll
      for (int i = 0; i < 4; ++i)
        bfr[i] = *(const s16x8*)&Bs[cur * 8192 + (rb + (i << 4)) * 64 + kk];
#pragma unroll
      for (int i = 0; i < 4; ++i)
#pragma unroll
        for (int j = 0; j < 4; ++j)
          acc[i][j] = __builtin_amdgcn_mfma_f32_16x16x32_bf16(af[i], bfr[j], acc[i][j], 0, 0, 0);
    }
    __syncthreads();                    // drains vmcnt -> next buffer ready
    cur ^= 1;
  }

  // Epilogue. C/D layout (m89-verified): col = lane&15, row = (lane>>4)*4 + reg
  if (EPI == 2) {
    unsigned short* C = (unsigned short*)Cv;
#pragma unroll
    for (int i = 0; i < 4; ++i) {
      const int lr0 = (wr << 6) + (i << 4) + ((lane >> 4) << 2);
#pragma unroll
      for (int j = 0; j < 4; ++j) {
        const int c = n0 + (wc << 6) + (j << 4) + (lane & 15);
#pragma unroll
        for (int rr = 0; rr < 4; ++rr) {
          const int lr = lr0 + rr;
          if (lr >= rlo && lr < rhi)
            C[(size_t)(m0 + lr) * ldc + c] = f2bf(acc[i][j][rr]);
        }
      }
    }
  } else if (EPI == 3) {
    float* C = (float*)Cv;
    float ob[4];
#pragma unroll
    for (int j = 0; j < 4; ++j)
      ob[j] = obias[n0 + (wc << 6) + (j << 4) + (lane & 15)];
#pragma unroll
    for (int i = 0; i < 4; ++i) {
      const int r0 = m0 + (wr << 6) + (i << 4) + ((lane >> 4) << 2);
#pragma unroll
      for (int j = 0; j < 4; ++j) {
        const int c = n0 + (wc << 6) + (j << 4) + (lane & 15);
#pragma unroll
        for (int rr = 0; rr < 4; ++rr)
          C[(size_t)(r0 + rr) * ldc + c] = acc[i][j][rr] + ob[j];
      }
    }
  } else {  // EPI == 4: bf16 out (n0==0) + per-chunk column sums of scanned streams
    unsigned short* C = (unsigned short*)Cv;
#pragma unroll
    for (int i = 0; i < 4; ++i) {
      const int r0 = m0 + (wr << 6) + (i << 4) + ((lane >> 4) << 2);
#pragma unroll
      for (int j = 0; j < 4; ++j) {
        const int c = (wc << 6) + (j << 4) + (lane & 15);
#pragma unroll
        for (int rr = 0; rr < 4; ++rr)
          C[(size_t)(r0 + rr) * ldc + c] = f2bf(acc[i][j][rr]);
      }
    }
    // streams: y=1: wc0->s2(off0), wc1->s6(off64); y=2 wc0->s3(off128); y=3 wc0->sZ(off192)
    int soff = -1;
    if (ygrp == 1) soff = wc << 6;
    else if (ygrp == 2 && wc == 0) soff = 128;
    else if (ygrp == 3 && wc == 0) soff = 192;
    if (soff >= 0) {
#pragma unroll
      for (int half = 0; half < 2; ++half) {   // two 32-row chunks per wave
        const int grow = m0 + (wr << 6) + (half << 5);
        const int b_ = grow >> 11, ch = (grow & 2047) >> 5;
#pragma unroll
        for (int j = 0; j < 4; ++j) {
          float v = 0.f;
#pragma unroll
          for (int i = half * 2; i < half * 2 + 2; ++i)
#pragma unroll
            for (int rr = 0; rr < 4; ++rr) v += acc[i][j][rr];
          v += __shfl_xor(v, 16);
          v += __shfl_xor(v, 32);
          if (lane < 16)
            sums[((b_ * 64 + ch) << 8) + soff + (j << 4) + lane] = v;
        }
      }
    }
  }
}

// ---------------------------------------------------------------------------
// Weight folds (single gemm call site each; 64KB LDS budget per kernel)
// ---------------------------------------------------------------------------
__global__ __launch_bounds__(256) void smallA_k(
    const unsigned short* BQ, const unsigned short* BK, const unsigned short* BI,
    const unsigned short* WOb, const unsigned short* WQt, const unsigned short* WKt,
    const unsigned short* Winvt, const unsigned short* UcatT,
    unsigned short* Gcat, unsigned short* Hb, unsigned short* Gfin)
{
  const int bx = blockIdx.x;
  const unsigned short *A, *B; unsigned short* C; int ldc, m0, n0;
  switch (blockIdx.y) {
    case 0:  A = BQ;  B = WQt;   C = Gcat;              ldc = 1024; m0 = 0; n0 = bx * 128; break;
    case 1:  A = BK;  B = WKt;   C = Gcat + 128 * 1024; ldc = 1024; m0 = 0; n0 = bx * 128; break;
    case 2:  A = BI;  B = Winvt; C = Hb;                ldc = 1024; m0 = 0; n0 = bx * 128; break;
    default: A = WOb; B = UcatT; C = Gfin;              ldc = 128;  m0 = bx * 128; n0 = 0; break;
  }
  gemm_body<2>(A, B, C, 1024, 1024, ldc, 1024, m0, n0, nullptr, nullptr, 0, 0, 128);
}

// G_P3 rows 0..63 -> Gcat rows 256..319 (s3); G_P4 rows 64..127 -> 320..383 (p4)
__global__ __launch_bounds__(256) void smallB_k(
    const unsigned short* Hb, const unsigned short* WKt, const unsigned short* WQt,
    unsigned short* Gcat)
{
  const int bx = blockIdx.x;
  const unsigned short* B = (blockIdx.y == 0) ? WKt : WQt;
  const int rlo = (blockIdx.y == 0) ? 0 : 64;
  gemm_body<2>(Hb, B, Gcat + 256 * 1024, 1024, 1024, 1024, 1024, 0, bx * 128,
               nullptr, nullptr, 0, rlo, rlo + 64);
}

// Pcat[8192][512] bf16 = xb @ Gcat^T; fused chunk-sum pass for scanned streams
__global__ __launch_bounds__(256) void mainP_k(
    const unsigned short* __restrict__ xb, const unsigned short* __restrict__ Gcat,
    unsigned short* __restrict__ Pcat, float* __restrict__ sums)
{
  const int y = blockIdx.y;
  gemm_body<4>(xb, Gcat + (size_t)y * 128 * 1024, Pcat + y * 128,
               1024, 1024, 512, 1024, blockIdx.x * 128, 0, nullptr, sums, y, 0, 128);
}

// out = rcat @ Gfin^T + obias  (M=8192, N=1024, K=128, fp32 out)
__global__ __launch_bounds__(256) void final_k(
    const unsigned short* __restrict__ rcat, const unsigned short* __restrict__ Gfin,
    const float* __restrict__ obias, float* __restrict__ out)
{
  gemm_body<3>(rcat, Gfin, out, 128, 128, 1024, 128,
               blockIdx.x * 128, blockIdx.y * 128, obias, nullptr, 0, 0, 128);
}

// ---------------------------------------------------------------------------
// Fused prep: cast x, transpose WQ/WK/Winv, build BQ/BK/BI, UcatT, X_t rows of
// Gcat, cast WO, obias reduction. Range-dispatched on blockIdx.x.
// ---------------------------------------------------------------------------
__global__ __launch_bounds__(256) void prep_k(
    const float* __restrict__ x, const float* __restrict__ WQ,
    const float* __restrict__ WK, const float* __restrict__ WO,
    const float* __restrict__ Winv, const float* __restrict__ U_b,
    const float* __restrict__ V_b, const float* __restrict__ W_b,
    const float* __restrict__ bias_b, const float* __restrict__ U_t,
    const float* __restrict__ V_t, const float* __restrict__ W_t,
    const float* __restrict__ X_t, const float* __restrict__ bias_t,
    const float* __restrict__ abi_p, const float* __restrict__ atri_p,
    unsigned short* xb, unsigned short* WQt, unsigned short* WKt,
    unsigned short* Winvt, unsigned short* WOb, unsigned short* BQ,
    unsigned short* BK, unsigned short* BI, unsigned short* UcatT,
    unsigned short* Gcat, float* obias)
{
  __shared__ float smem[64 * 65];
  const int bx = blockIdx.x, tid = threadIdx.x;
  if (bx < 8192) {                        // x -> bf16
    int i = bx * 256 + tid;
    float4 v = ((const float4*)x)[i];
    ushort4 o; o.x = f2bf(v.x); o.y = f2bf(v.y); o.z = f2bf(v.z); o.w = f2bf(v.w);
    ((ushort4*)xb)[i] = o;
  } else if (bx < 8960) {                 // transpose+cast WQ/WK/Winv
    int local = bx - 8192;
    const float* s; unsigned short* d;
    switch (local >> 8) { case 0: s = WQ; d = WQt; break;
                          case 1: s = WK; d = WKt; break;
                          default: s = Winv; d = Winvt; break; }
    int t = local & 255;
    int tY = t >> 4, tX = t & 15;
    int c = tid & 63, g = tid >> 6;
#pragma unroll
    for (int rr = 0; rr < 16; ++rr) {
      int r = g * 16 + rr;
      smem[r * 65 + c] = s[(size_t)(tY * 64 + r) * 1024 + tX * 64 + c];
    }
    __syncthreads();
#pragma unroll
    for (int rr = 0; rr < 16; ++rr) {
      int r = g * 16 + rr;
      d[(size_t)(tX * 64 + r) * 1024 + tY * 64 + c] = f2bf(smem[c * 65 + r]);
    }
  } else if (bx < 10496) {                // BQ/BK/BI panels [128][1024]
    int local = bx - 8960;
    const float *s0, *s1; unsigned short* d;
    switch (local >> 9) { case 0: s0 = V_b; s1 = V_t; d = BQ; break;
                          case 1: s0 = W_b; s1 = W_t; d = BK; break;
                          default: s0 = V_b; s1 = W_b; d = BI; break; }
    int idx = (local & 511) * 256 + tid;
    int n = idx >> 10, k = idx & 1023;
    const float* s = (n < 64) ? s0 : s1;
    d[idx] = f2bf(s[k * 64 + (n & 63)]);
  } else if (bx < 11008) {                // UcatT[128][1024]
    int idx = (bx - 10496) * 256 + tid;
    int k = idx >> 10, dd = idx & 1023;
    UcatT[idx] = f2bf(k < 64 ? U_b[dd * 64 + k] : U_t[dd * 64 + k - 64]);
  } else if (bx < 11520) {                // Gcat rows 384..511 = X_t^T (dup)
    int idx = (bx - 11008) * 256 + tid;
    int r = idx >> 10, dd = idx & 1023;
    Gcat[(size_t)384 * 1024 + idx] = f2bf(X_t[dd * 64 + (r & 63)]);
  } else if (bx < 12544) {                // WO -> bf16
    int i = (bx - 11520) * 256 + tid;
    float4 v = ((const float4*)WO)[i];
    ushort4 o; o.x = f2bf(v.x); o.y = f2bf(v.y); o.z = f2bf(v.z); o.w = f2bf(v.w);
    ((ushort4*)WOb)[i] = o;
  } else {                                // obias[n]
    int n = bx - 12544;
    const float abi = abi_p[0], atri = atri_p[0];
    float s = 0.f;
    for (int d0 = tid; d0 < 1024; d0 += 256)
      s += ((1.f + abi) * bias_b[d0] + atri * bias_t[d0]) * WO[(size_t)n * 1024 + d0];
    smem[tid] = s;
    __syncthreads();
#pragma unroll
    for (int w = 128; w > 0; w >>= 1) {
      if (tid < w) smem[tid] += smem[tid + w];
      __syncthreads();
    }
    if (tid == 0) obias[n] = smem[0];
  }
}

// ---------------------------------------------------------------------------
// scanB: carry from mainP's chunk sums, then 32 rows combine -> rcat bf16.
// Pcat cols: 0:p1 64:p5 128:s2 192:s6 256:s3 320:p4 384:sZ (ld=512)
// ---------------------------------------------------------------------------
__global__ __launch_bounds__(256) void scanB_k(
    const unsigned short* __restrict__ P, const float* __restrict__ sums,
    const float* __restrict__ abi_p, const float* __restrict__ atri_p,
    unsigned short* __restrict__ rcat)
{
  const int w = blockIdx.x * 4 + (threadIdx.x >> 6);
  const int lane = threadIdx.x & 63;
  const int b = w >> 6, ch = w & 63;
  float c2 = 0.f, c6 = 0.f, c3 = 0.f, cZ = 0.f;
  for (int i = 0; i < ch; ++i) {
    const float* s = sums + (((size_t)b * 64 + i) << 8) + lane;
    c2 += s[0]; c6 += s[64]; c3 += s[128]; cZ += s[192];
  }
  const float abi = abi_p[0], atri = atri_p[0];
  const size_t row0 = (size_t)b * T_LEN + ch * 32;
#pragma unroll 2
  for (int t = 0; t < 32; ++t) {
    const size_t ro = (row0 + t) * 512;
    const float p1 = bf2f(P[ro + lane]);
    const float p5 = bf2f(P[ro + 64 + lane]);
    c2 += bf2f(P[ro + 128 + lane]);
    c6 += bf2f(P[ro + 192 + lane]);
    c3 += bf2f(P[ro + 256 + lane]);
    const float p4 = bf2f(P[ro + 320 + lane]);
    cZ += bf2f(P[ro + 384 + lane]);
    const float invc = 1.0f / (float)(ch * 32 + t + 1);
    const float rb = (p1 * c2 + abi * (c3 * p4)) * invc;
    const float rt = atri * p5 * c6 * cZ * invc * invc;
    const size_t rro = (row0 + t) * 128;
    rcat[rro + lane]      = f2bf(rb);
    rcat[rro + 64 + lane] = f2bf(rt);
  }
}

// ---------------------------------------------------------------------------
extern "C" void kernel_launch(void* const* d_in, const int* in_sizes, int n_in,
                              void* d_out, int out_size, void* d_ws, size_t ws_size,
                              hipStream_t stream)
{
  const float* x      = (const float*)d_in[0];
  const float* WQ     = (const float*)d_in[1];
  const float* WK     = (const float*)d_in[2];
  const float* WO     = (const float*)d_in[3];
  const float* Winv   = (const float*)d_in[4];
  const float* U_b    = (const float*)d_in[5];
  const float* V_b    = (const float*)d_in[6];
  const float* W_b    = (const float*)d_in[7];
  const float* bias_b = (const float*)d_in[8];
  const float* U_t    = (const float*)d_in[9];
  const float* V_t    = (const float*)d_in[10];
  const float* W_t    = (const float*)d_in[11];
  const float* X_t    = (const float*)d_in[12];
  const float* bias_t = (const float*)d_in[13];
  const float* a_bi   = (const float*)d_in[14];
  const float* a_tri  = (const float*)d_in[15];

  char* ws = (char*)d_ws;
  size_t off = 0;
  unsigned short* xb    = (unsigned short*)(ws + off); off += (size_t)BT_DIM * 1024 * 2;  // 16MB
  unsigned short* Pcat  = (unsigned short*)(ws + off); off += (size_t)BT_DIM * 512 * 2;   // 8MB
  unsigned short* rcat  = (unsigned short*)(ws + off); off += (size_t)BT_DIM * 128 * 2;   // 2MB
  unsigned short* WQt   = (unsigned short*)(ws + off); off += 2097152;
  unsigned short* WKt   = (unsigned short*)(ws + off); off += 2097152;
  unsigned short* Winvt = (unsigned short*)(ws + off); off += 2097152;
  unsigned short* WOb   = (unsigned short*)(ws + off); off += 2097152;
  unsigned short* BQ    = (unsigned short*)(ws + off); off += 262144;
  unsigned short* BK    = (unsigned short*)(ws + off); off += 262144;
  unsigned short* BI    = (unsigned short*)(ws + off); off += 262144;
  unsigned short* Hb    = (unsigned short*)(ws + off); off += 262144;
  unsigned short* UcatT = (unsigned short*)(ws + off); off += 262144;
  unsigned short* Gcat  = (unsigned short*)(ws + off); off += (size_t)512 * 1024 * 2;     // 1MB
  unsigned short* Gfin  = (unsigned short*)(ws + off); off += 262144;
  float*          obias = (float*)(ws + off);          off += 4096;
  float*          sums  = (float*)(ws + off);          off += 262144;  // 256 chunks * 256 f32

  prep_k<<<dim3(13568), 256, 0, stream>>>(x, WQ, WK, WO, Winv, U_b, V_b, W_b, bias_b,
                                          U_t, V_t, W_t, X_t, bias_t, a_bi, a_tri,
                                          xb, WQt, WKt, Winvt, WOb, BQ, BK, BI,
                                          UcatT, Gcat, obias);
  smallA_k<<<dim3(8, 4), 256, 0, stream>>>(BQ, BK, BI, WOb, WQt, WKt, Winvt, UcatT,
                                           Gcat, Hb, Gfin);
  smallB_k<<<dim3(8, 2), 256, 0, stream>>>(Hb, WKt, WQt, Gcat);
  mainP_k<<<dim3(64, 4), 256, 0, stream>>>(xb, Gcat, Pcat, sums);
  scanB_k<<<dim3(64), 256, 0, stream>>>(Pcat, sums, a_bi, a_tri, rcat);
  final_k<<<dim3(64, 8), 256, 0, stream>>>(rcat, Gfin, obias, (float*)d_out);
}